// Round 1
// baseline (378.146 us; speedup 1.0000x reference)
//
#include <hip/hip_runtime.h>
#include <hip/hip_bf16.h>

// XCAttention: B=8, N=4096, C=768, H=32, D=24
// Pipeline:
//   K0a: x fp32 -> bf16
//   K0b: W_qkv, W_proj fp32 -> bf16 transposed (N x K) for "B^T" GEMM
//   K1 : qkv = x @ W_qkv + b_qkv       (bf16 MFMA GEMM, 32768x2304x768), bf16 out
//   K2 : per (b,h): Gram q^T k + norms via MFMA, softmax, y = attn @ v,
//        y written in (H,B,D,N) flat order (makes the torch-faithful reshape a no-op)
//   K3 : out = y @ W_proj + b_proj     (bf16 MFMA GEMM, 32768x768x768), fp32 out

#define DEVI __device__ __forceinline__

typedef __attribute__((ext_vector_type(8))) short bf16x8;
typedef __attribute__((ext_vector_type(4))) float f32x4;
typedef unsigned int u32;
typedef unsigned short u16;

DEVI u16 f2bf(float f) {  // RNE float->bf16
  union { float f; u32 u; } x; x.f = f;
  u32 r = x.u + 0x7FFFu + ((x.u >> 16) & 1u);
  return (u16)(r >> 16);
}

DEVI void gload_lds16(const void* g, void* l) {
  // async global->LDS, 16B per lane; LDS dest is wave-uniform base + lane*16
  __builtin_amdgcn_global_load_lds((__attribute__((address_space(1))) void*)g,
                                   (__attribute__((address_space(3))) void*)l, 16, 0, 0);
}

// ---------------- K0a: fp32 -> bf16 convert (vectorized) ----------------
__global__ __launch_bounds__(256) void cvt_kernel(const float* __restrict__ in,
                                                  u16* __restrict__ out, int n8) {
  int i = blockIdx.x * 256 + threadIdx.x;
  if (i >= n8) return;
  long o = (long)i * 8;
  float4 a = *(const float4*)(in + o);
  float4 b = *(const float4*)(in + o + 4);
  uint4 v;
  v.x = f2bf(a.x) | ((u32)f2bf(a.y) << 16);
  v.y = f2bf(a.z) | ((u32)f2bf(a.w) << 16);
  v.z = f2bf(b.x) | ((u32)f2bf(b.y) << 16);
  v.w = f2bf(b.z) | ((u32)f2bf(b.w) << 16);
  *(uint4*)(out + o) = v;
}

// ---------------- K0b: transpose + convert: W (K x N fp32) -> Wt (N x K bf16) ----------------
__global__ __launch_bounds__(256) void transpose_cvt(const float* __restrict__ W,
                                                     u16* __restrict__ Wt, int K, int N) {
  __shared__ float tile[32][33];
  int n0 = blockIdx.x * 32, k0 = blockIdx.y * 32;
  int tx = threadIdx.x, ty = threadIdx.y;  // (32,8)
  #pragma unroll
  for (int i = 0; i < 4; ++i)
    tile[ty + 8 * i][tx] = W[(long)(k0 + ty + 8 * i) * N + n0 + tx];
  __syncthreads();
  #pragma unroll
  for (int i = 0; i < 4; ++i)
    Wt[(long)(n0 + ty + 8 * i) * K + k0 + tx] = f2bf(tile[tx][ty + 8 * i]);
}

// ---------------- K1/K3: bf16 MFMA GEMM, C = A @ Bt^T + bias ----------------
// A: M x K bf16 row-major. Bt: N x K bf16 row-major. 128x128 tile, BK=64,
// 4 waves (2x2), each wave 64x64 (4x4 16x16 frags). m97-style global_load_lds staging.
template<int BF16_OUT>
__global__ __launch_bounds__(256) void gemm_bt_kernel(
    const u16* __restrict__ A, const u16* __restrict__ Bt,
    const float* __restrict__ bias, void* __restrict__ Cout,
    int M, int N, int K) {
  __shared__ u16 As[128 * 64];
  __shared__ u16 Bs[128 * 64];

  int nbx = N >> 7;
  int nwg = gridDim.x;
  int bid = blockIdx.x;
  // bijective XCD swizzle (grids are multiples of 8)
  bid = (bid & 7) * (nwg >> 3) + (bid >> 3);
  int bx = bid % nbx, by = bid / nbx;

  int t = threadIdx.x;
  int w = t >> 6, l = t & 63;
  int wr = w >> 1, wc = w & 1;
  int l16 = l & 15, l4 = l >> 4;

  f32x4 acc[4][4] = {};

  const u16* Ab = A + (long)by * 128 * K;
  const u16* Bb = Bt + (long)bx * 128 * K;

  for (int k0 = 0; k0 < K; k0 += 64) {
    #pragma unroll
    for (int c = 0; c < 4; ++c) {
      int o = (c * 256 + t) * 16;            // byte offset within 16KB tile
      int row = o >> 7;                      // 128B per row (64 bf16)
      int colb = o & 127;
      int ldsb = (c * 256 + (w << 6)) * 16;  // wave-uniform LDS base
      gload_lds16(Ab + (long)row * K + k0 + (colb >> 1), (char*)As + ldsb);
      gload_lds16(Bb + (long)row * K + k0 + (colb >> 1), (char*)Bs + ldsb);
    }
    __syncthreads();
    #pragma unroll
    for (int ks = 0; ks < 2; ++ks) {
      bf16x8 af[4], bfr[4];
      #pragma unroll
      for (int m = 0; m < 4; ++m)
        af[m] = *(const bf16x8*)&As[(wr * 64 + m * 16 + l16) * 64 + ks * 32 + l4 * 8];
      #pragma unroll
      for (int n = 0; n < 4; ++n)
        bfr[n] = *(const bf16x8*)&Bs[(wc * 64 + n * 16 + l16) * 64 + ks * 32 + l4 * 8];
      #pragma unroll
      for (int m = 0; m < 4; ++m)
        #pragma unroll
        for (int n = 0; n < 4; ++n)
          acc[m][n] = __builtin_amdgcn_mfma_f32_16x16x32_bf16(af[m], bfr[n], acc[m][n], 0, 0, 0);
    }
    __syncthreads();
  }

  #pragma unroll
  for (int m = 0; m < 4; ++m) {
    int row0 = by * 128 + wr * 64 + m * 16 + l4 * 4;
    #pragma unroll
    for (int n = 0; n < 4; ++n) {
      int col = bx * 128 + wc * 64 + n * 16 + l16;
      float bv = bias[col];
      #pragma unroll
      for (int j = 0; j < 4; ++j) {
        long idx = (long)(row0 + j) * N + col;
        float v = acc[m][n][j] + bv;
        if (BF16_OUT) ((u16*)Cout)[idx] = f2bf(v);
        else          ((float*)Cout)[idx] = v;
      }
    }
  }
}

// ---------------- K2: per-(b,h) XCA core ----------------
// Gram G = q^T k (24x24, K=4096) + diag(q^T q), diag(k^T k) via MFMA (D padded to 32),
// softmax over e with temperature, then y(d,n) = sum_e attn[d][e] v[n][e] via MFMA.
// y written at ((h*8+b)*24+d)*4096 + n  == flat (H,B,D,N) order.
__global__ __launch_bounds__(256) void attn_kernel(const u16* __restrict__ qkv,
                                                   const float* __restrict__ temperature,
                                                   u16* __restrict__ yout) {
  __shared__ u16 qt[32][136];    // [d][n] transposed q chunk (rows 24..31 stay zero)
  __shared__ u16 kt[32][136];
  __shared__ u16 vl[128][40];    // [n][e] natural v chunk (cols 24..39 stay zero)
  __shared__ u16 attnb[32][40];  // [d][e] softmax weights bf16 (pads stay zero)
  __shared__ float Gs[32][33];
  __shared__ float sq[32];
  __shared__ float sk[32];

  int bid = blockIdx.x;
  int b = bid >> 5, h = bid & 31;
  int t = threadIdx.x;
  int w = t >> 6, l = t & 63;
  int l16 = l & 15, l4 = l >> 4;
  int fm = w >> 1, fn = w & 1;

  for (int i = t; i < 32 * 136; i += 256) { qt[0][i] = 0; kt[0][i] = 0; }
  for (int i = t; i < 128 * 40; i += 256) vl[0][i] = 0;
  for (int i = t; i < 32 * 40; i += 256) attnb[0][i] = 0;
  __syncthreads();

  f32x4 accG = {}, accQ = {}, accK = {};
  const u16* qbase = qkv + (long)b * 4096 * 2304 + h * 24;

  // Phase 1: Gram + norms over all N in 128-row chunks
  for (int nc = 0; nc < 32; ++nc) {
    int n0 = nc * 128;
    #pragma unroll
    for (int i = 0; i < 6; ++i) {
      int idx = t + 256 * i;           // 1536 dwords per matrix per chunk
      int n = idx / 12, dw = idx % 12;
      const u16* p = qbase + (long)(n0 + n) * 2304 + dw * 2;
      u32 uq = *(const u32*)p;
      u32 uk = *(const u32*)(p + 768);
      qt[dw * 2][n] = (u16)uq; qt[dw * 2 + 1][n] = (u16)(uq >> 16);
      kt[dw * 2][n] = (u16)uk; kt[dw * 2 + 1][n] = (u16)(uk >> 16);
    }
    __syncthreads();
    #pragma unroll
    for (int ks = 0; ks < 4; ++ks) {
      int koff = ks * 32 + l4 * 8;
      bf16x8 qa = *(const bf16x8*)&qt[fm * 16 + l16][koff];
      bf16x8 qb = *(const bf16x8*)&qt[fn * 16 + l16][koff];
      bf16x8 ka = *(const bf16x8*)&kt[fm * 16 + l16][koff];
      bf16x8 kb = *(const bf16x8*)&kt[fn * 16 + l16][koff];
      accG = __builtin_amdgcn_mfma_f32_16x16x32_bf16(qa, kb, accG, 0, 0, 0);
      accQ = __builtin_amdgcn_mfma_f32_16x16x32_bf16(qa, qb, accQ, 0, 0, 0);
      accK = __builtin_amdgcn_mfma_f32_16x16x32_bf16(ka, kb, accK, 0, 0, 0);
    }
    __syncthreads();
  }

  #pragma unroll
  for (int j = 0; j < 4; ++j) Gs[fm * 16 + l4 * 4 + j][fn * 16 + l16] = accG[j];
  if (fm == fn) {
    #pragma unroll
    for (int j = 0; j < 4; ++j)
      if (l4 * 4 + j == l16) { sq[fm * 16 + l16] = accQ[j]; sk[fm * 16 + l16] = accK[j]; }
  }
  __syncthreads();

  // Phase 2: softmax rows (threads 0..23, one per d)
  if (t < 24) {
    float nq = fmaxf(sqrtf(fmaxf(sq[t], 0.f)), 1e-12f);
    float tmp = temperature[h];
    float p[24]; float mx = -1e30f;
    #pragma unroll
    for (int e = 0; e < 24; ++e) {
      float nk = fmaxf(sqrtf(fmaxf(sk[e], 0.f)), 1e-12f);
      float a = Gs[t][e] / (nq * nk) * tmp;
      p[e] = a; mx = fmaxf(mx, a);
    }
    float s = 0.f;
    #pragma unroll
    for (int e = 0; e < 24; ++e) { p[e] = __expf(p[e] - mx); s += p[e]; }
    float inv = 1.f / s;
    #pragma unroll
    for (int e = 0; e < 24; ++e) attnb[t][e] = f2bf(p[e] * inv);
  }
  __syncthreads();

  // Phase 3: y = attn @ v, chunked over n. A-frags (attn) hoisted.
  bf16x8 af0 = *(const bf16x8*)&attnb[l16][l4 * 8];
  bf16x8 af1 = *(const bf16x8*)&attnb[16 + l16][l4 * 8];
  const u16* vbase = qbase + 1536;
  u16* ybase = yout + (long)(h * 8 + b) * 24 * 4096;

  for (int nc = 0; nc < 32; ++nc) {
    int n0 = nc * 128;
    #pragma unroll
    for (int i = 0; i < 6; ++i) {
      int idx = t + 256 * i;
      int n = idx / 12, dw = idx % 12;
      u32 uv = *(const u32*)(vbase + (long)(n0 + n) * 2304 + dw * 2);
      *(u32*)&vl[n][dw * 2] = uv;
    }
    __syncthreads();
    f32x4 z = {};
    #pragma unroll
    for (int fnn = 0; fnn < 2; ++fnn) {
      int ncol = w * 32 + fnn * 16 + l16;
      bf16x8 bv = *(const bf16x8*)&vl[ncol][l4 * 8];
      f32x4 y0 = __builtin_amdgcn_mfma_f32_16x16x32_bf16(af0, bv, z, 0, 0, 0);
      f32x4 y1 = __builtin_amdgcn_mfma_f32_16x16x32_bf16(af1, bv, z, 0, 0, 0);
      int gn = n0 + ncol;
      #pragma unroll
      for (int j = 0; j < 4; ++j) {
        int d0 = l4 * 4 + j;
        ybase[(long)d0 * 4096 + gn] = f2bf(y0[j]);
        int d1 = 16 + d0;
        if (d1 < 24) ybase[(long)d1 * 4096 + gn] = f2bf(y1[j]);
      }
    }
    __syncthreads();
  }
}

extern "C" void kernel_launch(void* const* d_in, const int* in_sizes, int n_in,
                              void* d_out, int out_size, void* d_ws, size_t ws_size,
                              hipStream_t stream) {
  const float* x     = (const float*)d_in[0];
  const float* Wqkv  = (const float*)d_in[1];
  const float* bqkv  = (const float*)d_in[2];
  const float* temp  = (const float*)d_in[3];
  const float* Wproj = (const float*)d_in[4];
  const float* bproj = (const float*)d_in[5];
  float* out = (float*)d_out;

  char* ws = (char*)d_ws;
  u16* xb  = (u16*)(ws);              // 32768x768 bf16 (50,331,648 B)
  u16* wqt = (u16*)(ws + 50331648);   // 2304x768  bf16 (3,538,944 B)
  u16* wpt = (u16*)(ws + 53870592);   // 768x768   bf16 (1,179,648 B)
  u16* qkv = (u16*)(ws + 55050240);   // 32768x2304 bf16 (150,994,944 B) -> end 206,045,184
  u16* y   = xb;                      // overlap: x_bf16 dead after GEMM1 (stream-ordered)

  cvt_kernel<<<12288, 256, 0, stream>>>(x, xb, 3145728);
  transpose_cvt<<<dim3(72, 24), dim3(32, 8), 0, stream>>>(Wqkv, wqt, 768, 2304);
  transpose_cvt<<<dim3(24, 24), dim3(32, 8), 0, stream>>>(Wproj, wpt, 768, 768);
  gemm_bt_kernel<1><<<4608, 256, 0, stream>>>(xb, wqt, bqkv, qkv, 32768, 2304, 768);
  attn_kernel<<<256, 256, 0, stream>>>(qkv, temp, y);
  gemm_bt_kernel<0><<<1536, 256, 0, stream>>>(y, wpt, bproj, out, 32768, 768, 768);
}

// Round 2
// 322.009 us; speedup vs baseline: 1.1743x; 1.1743x over previous
//
#include <hip/hip_runtime.h>
#include <hip/hip_bf16.h>

// XCAttention: B=8, N=4096, C=768, H=32, D=24
// K0a: x fp32->bf16; K0b: W transposed->bf16; K1: qkv GEMM (8-phase 256^2);
// K2: per-(b,h) XCA core; K3: proj GEMM (8-phase 256^2), fp32 out.

#define DEVI __device__ __forceinline__

typedef __attribute__((ext_vector_type(8))) short bf16x8;
typedef __attribute__((ext_vector_type(4))) float f32x4;
typedef unsigned int u32;
typedef unsigned short u16;

DEVI u16 f2bf(float f) {  // RNE float->bf16
  union { float f; u32 u; } x; x.f = f;
  u32 r = x.u + 0x7FFFu + ((x.u >> 16) & 1u);
  return (u16)(r >> 16);
}

DEVI void gload_lds16(const void* g, void* l) {
  __builtin_amdgcn_global_load_lds((__attribute__((address_space(1))) void*)g,
                                   (__attribute__((address_space(3))) void*)l, 16, 0, 0);
}

// ---------------- K0a: fp32 -> bf16 convert ----------------
__global__ __launch_bounds__(256) void cvt_kernel(const float* __restrict__ in,
                                                  u16* __restrict__ out, int n8) {
  int i = blockIdx.x * 256 + threadIdx.x;
  if (i >= n8) return;
  long o = (long)i * 8;
  float4 a = *(const float4*)(in + o);
  float4 b = *(const float4*)(in + o + 4);
  uint4 v;
  v.x = f2bf(a.x) | ((u32)f2bf(a.y) << 16);
  v.y = f2bf(a.z) | ((u32)f2bf(a.w) << 16);
  v.z = f2bf(b.x) | ((u32)f2bf(b.y) << 16);
  v.w = f2bf(b.z) | ((u32)f2bf(b.w) << 16);
  *(uint4*)(out + o) = v;
}

// ---------------- K0b: W (K x N fp32) -> Wt (N x K bf16) ----------------
__global__ __launch_bounds__(256) void transpose_cvt(const float* __restrict__ W,
                                                     u16* __restrict__ Wt, int K, int N) {
  __shared__ float tile[32][33];
  int n0 = blockIdx.x * 32, k0 = blockIdx.y * 32;
  int tx = threadIdx.x, ty = threadIdx.y;  // (32,8)
  #pragma unroll
  for (int i = 0; i < 4; ++i)
    tile[ty + 8 * i][tx] = W[(long)(k0 + ty + 8 * i) * N + n0 + tx];
  __syncthreads();
  #pragma unroll
  for (int i = 0; i < 4; ++i)
    Wt[(long)(n0 + ty + 8 * i) * K + k0 + tx] = f2bf(tile[tx][ty + 8 * i]);
}

// ---------------- 8-phase 256x256 bf16 MFMA GEMM ----------------
// A: M x K row-major bf16. Bt: N x K row-major bf16. C = A@Bt^T + bias.
// 512 thr = 8 waves (2Mx4N), per-wave 128x64, BK=64, 2 K-tile dbuf slots.
// LDS per matrix slot: [ks(2)][row(256)][32 bf16] (64B rows), st_16x32 swizzle
// byte ^= ((byte>>9)&1)<<5 (applied to pre-swizzled gload source + ds_read addr).
// Schedule per tile kt (4 phases, read-ahead by 1 phase):
//   ph0: rd mq1 ; stage A(kt+1)    ph1: rd mq2 ; stage B(kt+2)
//   ph2: rd mq3 ; vmcnt(4)         ph3: rd mq0(kt+1)+B(kt+1)
// Each phase: issues ; sched_barrier ; s_barrier ; lgkmcnt(0) ; prio1 16xMFMA prio0 ; s_barrier.

#define MFMAQ(s, bs, q)                                                        \
  { _Pragma("unroll") for (int mi = 0; mi < 2; ++mi)                           \
    _Pragma("unroll") for (int n = 0; n < 4; ++n) {                            \
      acc[2*(q)+mi][n] = __builtin_amdgcn_mfma_f32_16x16x32_bf16(              \
          aR[s][mi*2+0], bR[bs][n*2+0], acc[2*(q)+mi][n], 0, 0, 0);            \
      acc[2*(q)+mi][n] = __builtin_amdgcn_mfma_f32_16x16x32_bf16(              \
          aR[s][mi*2+1], bR[bs][n*2+1], acc[2*(q)+mi][n], 0, 0, 0); } }

#define RDA(s, slot, q)                                                        \
  { _Pragma("unroll") for (int mi = 0; mi < 2; ++mi)                           \
    _Pragma("unroll") for (int ks = 0; ks < 2; ++ks)                           \
      aR[s][mi*2+ks] = *(const bf16x8*)(lds + (slot)*32768 + ks*16384 +        \
                                        (2*(q)+mi)*1024 + pA0); }

#define RDB(bs, slot)                                                          \
  { _Pragma("unroll") for (int n = 0; n < 4; ++n)                              \
    _Pragma("unroll") for (int ks = 0; ks < 2; ++ks)                           \
      bR[bs][n*2+ks] = *(const bf16x8*)(lds + (slot)*32768 + ks*16384 +        \
                                        n*1024 + pB0); }

#define STAGE(gbase, matoff, slot, ktile)                                      \
  { _Pragma("unroll") for (int j_ = 0; j_ < 2; ++j_)                           \
    _Pragma("unroll") for (int h_ = 0; h_ < 2; ++h_)                           \
      gload_lds16((gbase) + soff[j_] + (ktile) * 64 + h_ * 32,                 \
                  lds + (matoff) + (slot)*32768 + h_*16384 + sdst + j_*8192); }

#define PHASE_TAIL(SET, BS, Q)                                                 \
  __builtin_amdgcn_sched_barrier(0);                                           \
  __builtin_amdgcn_s_barrier();                                                \
  asm volatile("s_waitcnt lgkmcnt(0)" ::: "memory");                           \
  __builtin_amdgcn_sched_barrier(0);                                           \
  __builtin_amdgcn_s_setprio(1);                                               \
  MFMAQ(SET, BS, Q);                                                           \
  __builtin_amdgcn_s_setprio(0);                                               \
  __builtin_amdgcn_s_barrier();

template<int NT, int BF16_OUT>
__global__ __launch_bounds__(512, 2) void gemm8p_kernel(
    const u16* __restrict__ A, const u16* __restrict__ Bt,
    const float* __restrict__ bias, void* __restrict__ Cout,
    int M, int N) {
  constexpr int K = NT * 64;
  __shared__ __attribute__((aligned(128))) char lds[131072];

  int nbx = N >> 8;
  int nwg = gridDim.x;
  int bid = blockIdx.x;
  bid = (bid & 7) * (nwg >> 3) + (bid >> 3);  // bijective XCD swizzle (nwg%8==0)
  int bx = bid % nbx, by = bid / nbx;

  int t = threadIdx.x;
  int w = t >> 6, l = t & 63;
  int wr = w >> 2, wc = w & 3;
  int l16 = l & 15, l4 = l >> 4;

  // frag-read byte bases (swizzled)
  int rA = wr * 128 + l16, rB = wc * 64 + l16;
  int cbb = l4 * 16;
  int pA0 = rA * 64 + (cbb ^ (((rA >> 3) & 1) << 5));
  int pB0 = 65536 + rB * 64 + (cbb ^ (((rB >> 3) & 1) << 5));

  // stage source offsets (inverse-swizzled) for chunks t, t+512
  int soff[2];
  #pragma unroll
  for (int j = 0; j < 2; ++j) {
    int pin = (j * 512 + t) * 16;
    int inb = pin ^ (((pin >> 9) & 1) << 5);
    soff[j] = (inb >> 6) * K + ((inb & 63) >> 1);
  }
  const u16* Ag = A + (long)by * 256 * K;
  const u16* Bg = Bt + (long)bx * 256 * K;
  int sdst = w * 1024;  // wave-uniform LDS stage dest base (bytes)

  f32x4 acc[8][4] = {};
  bf16x8 aR[2][4], bR[2][8];

  // ---- prologue: A(0),B(0)->slot0, B(1)->slot1 ----
  STAGE(Ag, 0, 0, 0);
  STAGE(Bg, 65536, 0, 0);
  STAGE(Bg, 65536, 1, 1);
  asm volatile("s_waitcnt vmcnt(4)" ::: "memory");
  __builtin_amdgcn_s_barrier();
  RDA(0, 0, 0);
  RDB(0, 0);

  const int niter = NT / 2;
  for (int it = 0; it < niter; ++it) {
    int kt = it * 2;
    bool nl = (it < niter - 1);
    // pi0: MFMA q0 tile kt (slot0,set0,bR0); rd mq1->set1; stage A(kt+1)->slot1
    RDA(1, 0, 1);
    STAGE(Ag, 0, 1, kt + 1);
    PHASE_TAIL(0, 0, 0)
    // pi1: MFMA q1; rd mq2->set0; stage B(kt+2)->slot0
    RDA(0, 0, 2);
    if (nl) STAGE(Bg, 65536, 0, kt + 2);
    PHASE_TAIL(1, 0, 1)
    // pi2: MFMA q2; rd mq3->set1; vmcnt
    RDA(1, 0, 3);
    if (nl) asm volatile("s_waitcnt vmcnt(4)" ::: "memory");
    else    asm volatile("s_waitcnt vmcnt(0)" ::: "memory");
    PHASE_TAIL(0, 0, 2)
    // pi3: MFMA q3; rd mq0(kt+1,slot1)->set0 + B(kt+1)->bR1
    RDA(0, 1, 0);
    RDB(1, 1);
    PHASE_TAIL(1, 0, 3)
    // pi4: tile kt+1: MFMA q0 (set0,bR1); rd mq1->set1; stage A(kt+2)->slot0
    RDA(1, 1, 1);
    if (nl) STAGE(Ag, 0, 0, kt + 2);
    PHASE_TAIL(0, 1, 0)
    // pi5: MFMA q1; rd mq2->set0; stage B(kt+3)->slot1
    RDA(0, 1, 2);
    if (nl) STAGE(Bg, 65536, 1, kt + 3);
    PHASE_TAIL(1, 1, 1)
    // pi6: MFMA q2; rd mq3->set1; vmcnt
    RDA(1, 1, 3);
    if (nl) asm volatile("s_waitcnt vmcnt(4)" ::: "memory");
    PHASE_TAIL(0, 1, 2)
    // pi7: MFMA q3; rd mq0(kt+2,slot0)->set0 + B(kt+2)->bR0
    if (nl) { RDA(0, 0, 0); RDB(0, 0); }
    PHASE_TAIL(1, 1, 3)
  }

  // ---- epilogue ----
  #pragma unroll
  for (int m = 0; m < 8; ++m) {
    int row0 = by * 256 + wr * 128 + m * 16 + l4 * 4;
    #pragma unroll
    for (int n = 0; n < 4; ++n) {
      int col = bx * 256 + wc * 64 + n * 16 + l16;
      float bv = bias[col];
      #pragma unroll
      for (int j = 0; j < 4; ++j) {
        long idx = (long)(row0 + j) * N + col;
        float v = acc[m][n][j] + bv;
        if (BF16_OUT) ((u16*)Cout)[idx] = f2bf(v);
        else          ((float*)Cout)[idx] = v;
      }
    }
  }
}

// ---------------- K2: per-(b,h) XCA core ----------------
__global__ __launch_bounds__(256) void attn_kernel(const u16* __restrict__ qkv,
                                                   const float* __restrict__ temperature,
                                                   u16* __restrict__ yout) {
  __shared__ u16 qt[32][136];
  __shared__ u16 kt[32][136];
  __shared__ u16 vl[128][40];
  __shared__ u16 attnb[32][40];
  __shared__ float Gs[32][33];
  __shared__ float sq[32];
  __shared__ float sk[32];

  int bid = blockIdx.x;
  int b = bid >> 5, h = bid & 31;
  int t = threadIdx.x;
  int w = t >> 6, l = t & 63;
  int l16 = l & 15, l4 = l >> 4;
  int fm = w >> 1, fn = w & 1;

  for (int i = t; i < 32 * 136; i += 256) { qt[0][i] = 0; kt[0][i] = 0; }
  for (int i = t; i < 128 * 40; i += 256) vl[0][i] = 0;
  for (int i = t; i < 32 * 40; i += 256) attnb[0][i] = 0;
  __syncthreads();

  f32x4 accG = {}, accQ = {}, accK = {};
  const u16* qbase = qkv + (long)b * 4096 * 2304 + h * 24;

  for (int nc = 0; nc < 32; ++nc) {
    int n0 = nc * 128;
    #pragma unroll
    for (int i = 0; i < 6; ++i) {
      int idx = t + 256 * i;
      int n = idx / 12, dw = idx % 12;
      const u16* p = qbase + (long)(n0 + n) * 2304 + dw * 2;
      u32 uq = *(const u32*)p;
      u32 uk = *(const u32*)(p + 768);
      qt[dw * 2][n] = (u16)uq; qt[dw * 2 + 1][n] = (u16)(uq >> 16);
      kt[dw * 2][n] = (u16)uk; kt[dw * 2 + 1][n] = (u16)(uk >> 16);
    }
    __syncthreads();
    #pragma unroll
    for (int ks = 0; ks < 4; ++ks) {
      int koff = ks * 32 + l4 * 8;
      bf16x8 qa = *(const bf16x8*)&qt[fm * 16 + l16][koff];
      bf16x8 qb = *(const bf16x8*)&qt[fn * 16 + l16][koff];
      bf16x8 ka = *(const bf16x8*)&kt[fm * 16 + l16][koff];
      bf16x8 kb = *(const bf16x8*)&kt[fn * 16 + l16][koff];
      accG = __builtin_amdgcn_mfma_f32_16x16x32_bf16(qa, kb, accG, 0, 0, 0);
      accQ = __builtin_amdgcn_mfma_f32_16x16x32_bf16(qa, qb, accQ, 0, 0, 0);
      accK = __builtin_amdgcn_mfma_f32_16x16x32_bf16(ka, kb, accK, 0, 0, 0);
    }
    __syncthreads();
  }

  #pragma unroll
  for (int j = 0; j < 4; ++j) Gs[fm * 16 + l4 * 4 + j][fn * 16 + l16] = accG[j];
  if (fm == fn) {
    #pragma unroll
    for (int j = 0; j < 4; ++j)
      if (l4 * 4 + j == l16) { sq[fm * 16 + l16] = accQ[j]; sk[fm * 16 + l16] = accK[j]; }
  }
  __syncthreads();

  if (t < 24) {
    float nq = fmaxf(sqrtf(fmaxf(sq[t], 0.f)), 1e-12f);
    float tmp = temperature[h];
    float p[24]; float mx = -1e30f;
    #pragma unroll
    for (int e = 0; e < 24; ++e) {
      float nk = fmaxf(sqrtf(fmaxf(sk[e], 0.f)), 1e-12f);
      float a = Gs[t][e] / (nq * nk) * tmp;
      p[e] = a; mx = fmaxf(mx, a);
    }
    float s = 0.f;
    #pragma unroll
    for (int e = 0; e < 24; ++e) { p[e] = __expf(p[e] - mx); s += p[e]; }
    float inv = 1.f / s;
    #pragma unroll
    for (int e = 0; e < 24; ++e) attnb[t][e] = f2bf(p[e] * inv);
  }
  __syncthreads();

  bf16x8 af0 = *(const bf16x8*)&attnb[l16][l4 * 8];
  bf16x8 af1 = *(const bf16x8*)&attnb[16 + l16][l4 * 8];
  const u16* vbase = qbase + 1536;
  u16* ybase = yout + (long)(h * 8 + b) * 24 * 4096;

  for (int nc = 0; nc < 32; ++nc) {
    int n0 = nc * 128;
    #pragma unroll
    for (int i = 0; i < 6; ++i) {
      int idx = t + 256 * i;
      int n = idx / 12, dw = idx % 12;
      u32 uv = *(const u32*)(vbase + (long)(n0 + n) * 2304 + dw * 2);
      *(u32*)&vl[n][dw * 2] = uv;
    }
    __syncthreads();
    f32x4 z = {};
    #pragma unroll
    for (int fnn = 0; fnn < 2; ++fnn) {
      int ncol = w * 32 + fnn * 16 + l16;
      bf16x8 bv = *(const bf16x8*)&vl[ncol][l4 * 8];
      f32x4 y0 = __builtin_amdgcn_mfma_f32_16x16x32_bf16(af0, bv, z, 0, 0, 0);
      f32x4 y1 = __builtin_amdgcn_mfma_f32_16x16x32_bf16(af1, bv, z, 0, 0, 0);
      int gn = n0 + ncol;
      #pragma unroll
      for (int j = 0; j < 4; ++j) {
        int d0 = l4 * 4 + j;
        ybase[(long)d0 * 4096 + gn] = f2bf(y0[j]);
        int d1 = 16 + d0;
        if (d1 < 24) ybase[(long)d1 * 4096 + gn] = f2bf(y1[j]);
      }
    }
    __syncthreads();
  }
}

extern "C" void kernel_launch(void* const* d_in, const int* in_sizes, int n_in,
                              void* d_out, int out_size, void* d_ws, size_t ws_size,
                              hipStream_t stream) {
  const float* x     = (const float*)d_in[0];
  const float* Wqkv  = (const float*)d_in[1];
  const float* bqkv  = (const float*)d_in[2];
  const float* temp  = (const float*)d_in[3];
  const float* Wproj = (const float*)d_in[4];
  const float* bproj = (const float*)d_in[5];
  float* out = (float*)d_out;

  char* ws = (char*)d_ws;
  u16* xb  = (u16*)(ws);              // 32768x768 bf16
  u16* wqt = (u16*)(ws + 50331648);   // 2304x768  bf16
  u16* wpt = (u16*)(ws + 53870592);   // 768x768   bf16
  u16* qkv = (u16*)(ws + 55050240);   // 32768x2304 bf16
  u16* y   = xb;                      // x_bf16 dead after GEMM1

  cvt_kernel<<<12288, 256, 0, stream>>>(x, xb, 3145728);
  transpose_cvt<<<dim3(72, 24), dim3(32, 8), 0, stream>>>(Wqkv, wqt, 768, 2304);
  transpose_cvt<<<dim3(24, 24), dim3(32, 8), 0, stream>>>(Wproj, wpt, 768, 768);
  gemm8p_kernel<12, 1><<<1152, 512, 0, stream>>>(xb, wqt, bqkv, qkv, 32768, 2304);
  attn_kernel<<<256, 256, 0, stream>>>(qkv, temp, y);
  gemm8p_kernel<12, 0><<<384, 512, 0, stream>>>(y, wpt, bproj, out, 32768, 768);
}

// Round 3
// 316.571 us; speedup vs baseline: 1.1945x; 1.0172x over previous
//
#include <hip/hip_runtime.h>
#include <hip/hip_bf16.h>

// XCAttention: B=8, N=4096, C=768, H=32, D=24
// K0a: x fp32->bf16; K0b: W transposed->bf16; K1: qkv GEMM (8-phase 256x256);
// K2: per-(b,h) XCA core; K3: proj GEMM (8-phase 128x256), fp32 out.

#define DEVI __device__ __forceinline__

typedef __attribute__((ext_vector_type(8))) short bf16x8;
typedef __attribute__((ext_vector_type(4))) float f32x4;
typedef unsigned int u32;
typedef unsigned short u16;

DEVI u16 f2bf(float f) {  // RNE float->bf16
  union { float f; u32 u; } x; x.f = f;
  u32 r = x.u + 0x7FFFu + ((x.u >> 16) & 1u);
  return (u16)(r >> 16);
}

DEVI void gload_lds16(const void* g, void* l) {
  __builtin_amdgcn_global_load_lds((__attribute__((address_space(1))) void*)g,
                                   (__attribute__((address_space(3))) void*)l, 16, 0, 0);
}

// ---------------- K0a: fp32 -> bf16 convert ----------------
__global__ __launch_bounds__(256) void cvt_kernel(const float* __restrict__ in,
                                                  u16* __restrict__ out, int n8) {
  int i = blockIdx.x * 256 + threadIdx.x;
  if (i >= n8) return;
  long o = (long)i * 8;
  float4 a = *(const float4*)(in + o);
  float4 b = *(const float4*)(in + o + 4);
  uint4 v;
  v.x = f2bf(a.x) | ((u32)f2bf(a.y) << 16);
  v.y = f2bf(a.z) | ((u32)f2bf(a.w) << 16);
  v.z = f2bf(b.x) | ((u32)f2bf(b.y) << 16);
  v.w = f2bf(b.z) | ((u32)f2bf(b.w) << 16);
  *(uint4*)(out + o) = v;
}

// ---------------- K0b: W (K x N fp32) -> Wt (N x K bf16) ----------------
__global__ __launch_bounds__(256) void transpose_cvt(const float* __restrict__ W,
                                                     u16* __restrict__ Wt, int K, int N) {
  __shared__ float tile[32][33];
  int n0 = blockIdx.x * 32, k0 = blockIdx.y * 32;
  int tx = threadIdx.x, ty = threadIdx.y;  // (32,8)
  #pragma unroll
  for (int i = 0; i < 4; ++i)
    tile[ty + 8 * i][tx] = W[(long)(k0 + ty + 8 * i) * N + n0 + tx];
  __syncthreads();
  #pragma unroll
  for (int i = 0; i < 4; ++i)
    Wt[(long)(n0 + ty + 8 * i) * K + k0 + tx] = f2bf(tile[tx][ty + 8 * i]);
}

// ---------------- 8-phase BMx256 bf16 MFMA GEMM ----------------
// A: M x K row-major bf16. Bt: N x K row-major bf16. C = A@Bt^T + bias.
// 512 thr = 8 waves (2Mx4N), per-wave (BM/2)x64, BK=64, 2 K-tile dbuf slots.
// LDS per A slot: [ks(2)][row(BM)][32 bf16] (64B rows); B slot 256 rows.
// st_16x32 swizzle byte ^= ((byte>>9)&1)<<5 (pre-swizzled gload source + ds_read addr).
// Counted waits only: no lgkmcnt(0) in loop (compiler emits counted waits from
// data deps; reads are consumed one phase after issue), vmcnt(4) twice per 2 tiles.

#define MFMAQ(s, bs, q)                                                        \
  { _Pragma("unroll") for (int mi = 0; mi < MI; ++mi)                          \
    _Pragma("unroll") for (int n = 0; n < 4; ++n) {                            \
      acc[MI*(q)+mi][n] = __builtin_amdgcn_mfma_f32_16x16x32_bf16(             \
          aR[s][mi*2+0], bR[bs][n*2+0], acc[MI*(q)+mi][n], 0, 0, 0);           \
      acc[MI*(q)+mi][n] = __builtin_amdgcn_mfma_f32_16x16x32_bf16(             \
          aR[s][mi*2+1], bR[bs][n*2+1], acc[MI*(q)+mi][n], 0, 0, 0); } }

#define RDA(s, slot, q)                                                        \
  { _Pragma("unroll") for (int mi = 0; mi < MI; ++mi)                          \
    _Pragma("unroll") for (int ks = 0; ks < 2; ++ks)                           \
      aR[s][mi*2+ks] = *(const bf16x8*)(lds + (slot)*SLOT_A + ks*KS_A +        \
                                        (MI*(q)+mi)*1024 + pA0); }

#define RDB(bs, slot)                                                          \
  { _Pragma("unroll") for (int n = 0; n < 4; ++n)                              \
    _Pragma("unroll") for (int ks = 0; ks < 2; ++ks)                           \
      bR[bs][n*2+ks] = *(const bf16x8*)(lds + BOFF + (slot)*32768 + ks*16384 + \
                                        n*1024 + pB0); }

#define STAGE_A(slot, ktile)                                                   \
  { _Pragma("unroll") for (int j_ = 0; j_ < JA; ++j_)                          \
    _Pragma("unroll") for (int h_ = 0; h_ < 2; ++h_)                           \
      gload_lds16(Ag + soff[j_] + (ktile) * 64 + h_ * 32,                      \
                  lds + (slot)*SLOT_A + h_*KS_A + sdst + j_*8192); }

#define STAGE_B(slot, ktile)                                                   \
  { _Pragma("unroll") for (int j_ = 0; j_ < 2; ++j_)                           \
    _Pragma("unroll") for (int h_ = 0; h_ < 2; ++h_)                           \
      gload_lds16(Bg + soff[j_] + (ktile) * 64 + h_ * 32,                      \
                  lds + BOFF + (slot)*32768 + h_*16384 + sdst + j_*8192); }

#define PHASE_TAIL(SET, BS, Q)                                                 \
  __builtin_amdgcn_sched_barrier(0);                                           \
  __builtin_amdgcn_s_barrier();                                                \
  __builtin_amdgcn_sched_barrier(0);                                           \
  __builtin_amdgcn_s_setprio(1);                                               \
  MFMAQ(SET, BS, Q);                                                           \
  __builtin_amdgcn_s_setprio(0);                                               \
  __builtin_amdgcn_s_barrier();                                                \
  __builtin_amdgcn_sched_barrier(0);

template<int NT, int MFRAG, int BF16_OUT>
__global__ __launch_bounds__(512, 2) void gemm8p_kernel(
    const u16* __restrict__ A, const u16* __restrict__ Bt,
    const float* __restrict__ bias, void* __restrict__ Cout,
    int M, int N) {
  constexpr int K = NT * 64;
  constexpr int MI = MFRAG / 4;        // m-frags per quadrant
  constexpr int BM = MFRAG * 32;       // 256 or 128
  constexpr int SLOT_A = BM * 128;     // bytes per A slot
  constexpr int KS_A = BM * 64;
  constexpr int BOFF = 2 * SLOT_A;     // B region base
  constexpr int JA = BM / 128;         // per-thread A stage chunks
  __shared__ __attribute__((aligned(128))) char lds[BOFF + 65536];

  int nbx = N >> 8;
  int nwg = gridDim.x;
  int bid = blockIdx.x;
  bid = (bid & 7) * (nwg >> 3) + (bid >> 3);  // bijective XCD swizzle (nwg%8==0)
  int bx = bid % nbx, by = bid / nbx;

  int t = threadIdx.x;
  int w = t >> 6, l = t & 63;
  int wr = w >> 2, wc = w & 3;
  int l16 = l & 15, l4 = l >> 4;

  // frag-read byte bases (swizzled)
  int rA = wr * (MFRAG * 16) + l16, rB = wc * 64 + l16;
  int cbb = l4 * 16;
  int pA0 = rA * 64 + (cbb ^ (((rA >> 3) & 1) << 5));
  int pB0 = rB * 64 + (cbb ^ (((rB >> 3) & 1) << 5));

  // stage source offsets (inverse-swizzled) for chunks t, t+512
  int soff[2];
  #pragma unroll
  for (int j = 0; j < 2; ++j) {
    int pin = (j * 512 + t) * 16;
    int inb = pin ^ (((pin >> 9) & 1) << 5);
    soff[j] = (inb >> 6) * K + ((inb & 63) >> 1);
  }
  const u16* Ag = A + (long)by * BM * K;
  const u16* Bg = Bt + (long)bx * 256 * K;
  int sdst = w * 1024;  // wave-uniform LDS stage dest base (bytes)

  f32x4 acc[MFRAG][4] = {};
  bf16x8 aR[2][2 * MI], bR[2][8];

  // ---- prologue: A(0),B(0)->slot0, B(1)->slot1 ----
  STAGE_A(0, 0);
  STAGE_B(0, 0);
  STAGE_B(1, 1);
  asm volatile("s_waitcnt vmcnt(4)" ::: "memory");
  __builtin_amdgcn_s_barrier();
  RDA(0, 0, 0);
  RDB(0, 0);

  const int niter = NT / 2;
  for (int it = 0; it < niter; ++it) {
    int kt = it * 2;
    bool nl = (it < niter - 1);
    // pi0: MFMA q0 tile kt (slot0,set0,bR0); rd mq1->set1; stage A(kt+1)->slot1
    RDA(1, 0, 1);
    STAGE_A(1, kt + 1);
    PHASE_TAIL(0, 0, 0)
    // pi1: MFMA q1; rd mq2->set0; stage B(kt+2)->slot0
    RDA(0, 0, 2);
    if (nl) STAGE_B(0, kt + 2);
    PHASE_TAIL(1, 0, 1)
    // pi2: MFMA q2; rd mq3->set1; vmcnt
    RDA(1, 0, 3);
    if (nl) asm volatile("s_waitcnt vmcnt(4)" ::: "memory");
    else    asm volatile("s_waitcnt vmcnt(0)" ::: "memory");
    PHASE_TAIL(0, 0, 2)
    // pi3: MFMA q3; rd mq0(kt+1,slot1)->set0 + B(kt+1)->bR1
    RDA(0, 1, 0);
    RDB(1, 1);
    PHASE_TAIL(1, 0, 3)
    // pi4: tile kt+1: MFMA q0 (set0,bR1); rd mq1->set1; stage A(kt+2)->slot0
    RDA(1, 1, 1);
    if (nl) STAGE_A(0, kt + 2);
    PHASE_TAIL(0, 1, 0)
    // pi5: MFMA q1; rd mq2->set0; stage B(kt+3)->slot1
    RDA(0, 1, 2);
    if (nl) STAGE_B(1, kt + 3);
    PHASE_TAIL(1, 1, 1)
    // pi6: MFMA q2; rd mq3->set1; vmcnt
    RDA(1, 1, 3);
    if (nl) asm volatile("s_waitcnt vmcnt(4)" ::: "memory");
    PHASE_TAIL(0, 1, 2)
    // pi7: MFMA q3; rd mq0(kt+2,slot0)->set0 + B(kt+2)->bR0
    if (nl) { RDA(0, 0, 0); RDB(0, 0); }
    PHASE_TAIL(1, 1, 3)
  }

  // ---- epilogue ----
  #pragma unroll
  for (int m = 0; m < MFRAG; ++m) {
    int row0 = by * BM + wr * (MFRAG * 16) + m * 16 + l4 * 4;
    #pragma unroll
    for (int n = 0; n < 4; ++n) {
      int col = bx * 256 + wc * 64 + n * 16 + l16;
      float bv = bias[col];
      #pragma unroll
      for (int j = 0; j < 4; ++j) {
        long idx = (long)(row0 + j) * N + col;
        float v = acc[m][n][j] + bv;
        if (BF16_OUT) ((u16*)Cout)[idx] = f2bf(v);
        else          ((float*)Cout)[idx] = v;
      }
    }
  }
}

// ---------------- K2: per-(b,h) XCA core ----------------
__global__ __launch_bounds__(256) void attn_kernel(const u16* __restrict__ qkv,
                                                   const float* __restrict__ temperature,
                                                   u16* __restrict__ yout) {
  __shared__ u16 qt[32][136];
  __shared__ u16 kt[32][136];
  __shared__ u16 vl[128][40];
  __shared__ u16 attnb[32][40];
  __shared__ float Gs[32][33];
  __shared__ float sq[32];
  __shared__ float sk[32];

  int bid = blockIdx.x;
  int b = bid >> 5, h = bid & 31;
  int t = threadIdx.x;
  int w = t >> 6, l = t & 63;
  int l16 = l & 15, l4 = l >> 4;
  int fm = w >> 1, fn = w & 1;

  for (int i = t; i < 32 * 136; i += 256) { qt[0][i] = 0; kt[0][i] = 0; }
  for (int i = t; i < 128 * 40; i += 256) vl[0][i] = 0;
  for (int i = t; i < 32 * 40; i += 256) attnb[0][i] = 0;
  __syncthreads();

  f32x4 accG = {}, accQ = {}, accK = {};
  const u16* qbase = qkv + (long)b * 4096 * 2304 + h * 24;

  for (int nc = 0; nc < 32; ++nc) {
    int n0 = nc * 128;
    #pragma unroll
    for (int i = 0; i < 6; ++i) {
      int idx = t + 256 * i;
      int n = idx / 12, dw = idx % 12;
      const u16* p = qbase + (long)(n0 + n) * 2304 + dw * 2;
      u32 uq = *(const u32*)p;
      u32 uk = *(const u32*)(p + 768);
      qt[dw * 2][n] = (u16)uq; qt[dw * 2 + 1][n] = (u16)(uq >> 16);
      kt[dw * 2][n] = (u16)uk; kt[dw * 2 + 1][n] = (u16)(uk >> 16);
    }
    __syncthreads();
    #pragma unroll
    for (int ks = 0; ks < 4; ++ks) {
      int koff = ks * 32 + l4 * 8;
      bf16x8 qa = *(const bf16x8*)&qt[fm * 16 + l16][koff];
      bf16x8 qb = *(const bf16x8*)&qt[fn * 16 + l16][koff];
      bf16x8 ka = *(const bf16x8*)&kt[fm * 16 + l16][koff];
      bf16x8 kb = *(const bf16x8*)&kt[fn * 16 + l16][koff];
      accG = __builtin_amdgcn_mfma_f32_16x16x32_bf16(qa, kb, accG, 0, 0, 0);
      accQ = __builtin_amdgcn_mfma_f32_16x16x32_bf16(qa, qb, accQ, 0, 0, 0);
      accK = __builtin_amdgcn_mfma_f32_16x16x32_bf16(ka, kb, accK, 0, 0, 0);
    }
    __syncthreads();
  }

  #pragma unroll
  for (int j = 0; j < 4; ++j) Gs[fm * 16 + l4 * 4 + j][fn * 16 + l16] = accG[j];
  if (fm == fn) {
    #pragma unroll
    for (int j = 0; j < 4; ++j)
      if (l4 * 4 + j == l16) { sq[fm * 16 + l16] = accQ[j]; sk[fm * 16 + l16] = accK[j]; }
  }
  __syncthreads();

  if (t < 24) {
    float nq = fmaxf(sqrtf(fmaxf(sq[t], 0.f)), 1e-12f);
    float tmp = temperature[h];
    float p[24]; float mx = -1e30f;
    #pragma unroll
    for (int e = 0; e < 24; ++e) {
      float nk = fmaxf(sqrtf(fmaxf(sk[e], 0.f)), 1e-12f);
      float a = Gs[t][e] / (nq * nk) * tmp;
      p[e] = a; mx = fmaxf(mx, a);
    }
    float s = 0.f;
    #pragma unroll
    for (int e = 0; e < 24; ++e) { p[e] = __expf(p[e] - mx); s += p[e]; }
    float inv = 1.f / s;
    #pragma unroll
    for (int e = 0; e < 24; ++e) attnb[t][e] = f2bf(p[e] * inv);
  }
  __syncthreads();

  bf16x8 af0 = *(const bf16x8*)&attnb[l16][l4 * 8];
  bf16x8 af1 = *(const bf16x8*)&attnb[16 + l16][l4 * 8];
  const u16* vbase = qbase + 1536;
  u16* ybase = yout + (long)(h * 8 + b) * 24 * 4096;

  for (int nc = 0; nc < 32; ++nc) {
    int n0 = nc * 128;
    #pragma unroll
    for (int i = 0; i < 6; ++i) {
      int idx = t + 256 * i;
      int n = idx / 12, dw = idx % 12;
      u32 uv = *(const u32*)(vbase + (long)(n0 + n) * 2304 + dw * 2);
      *(u32*)&vl[n][dw * 2] = uv;
    }
    __syncthreads();
    f32x4 z = {};
    #pragma unroll
    for (int fnn = 0; fnn < 2; ++fnn) {
      int ncol = w * 32 + fnn * 16 + l16;
      bf16x8 bv = *(const bf16x8*)&vl[ncol][l4 * 8];
      f32x4 y0 = __builtin_amdgcn_mfma_f32_16x16x32_bf16(af0, bv, z, 0, 0, 0);
      f32x4 y1 = __builtin_amdgcn_mfma_f32_16x16x32_bf16(af1, bv, z, 0, 0, 0);
      int gn = n0 + ncol;
      #pragma unroll
      for (int j = 0; j < 4; ++j) {
        int d0 = l4 * 4 + j;
        ybase[(long)d0 * 4096 + gn] = f2bf(y0[j]);
        int d1 = 16 + d0;
        if (d1 < 24) ybase[(long)d1 * 4096 + gn] = f2bf(y1[j]);
      }
    }
    __syncthreads();
  }
}

extern "C" void kernel_launch(void* const* d_in, const int* in_sizes, int n_in,
                              void* d_out, int out_size, void* d_ws, size_t ws_size,
                              hipStream_t stream) {
  const float* x     = (const float*)d_in[0];
  const float* Wqkv  = (const float*)d_in[1];
  const float* bqkv  = (const float*)d_in[2];
  const float* temp  = (const float*)d_in[3];
  const float* Wproj = (const float*)d_in[4];
  const float* bproj = (const float*)d_in[5];
  float* out = (float*)d_out;

  char* ws = (char*)d_ws;
  u16* xb  = (u16*)(ws);              // 32768x768 bf16
  u16* wqt = (u16*)(ws + 50331648);   // 2304x768  bf16
  u16* wpt = (u16*)(ws + 53870592);   // 768x768   bf16
  u16* qkv = (u16*)(ws + 55050240);   // 32768x2304 bf16
  u16* y   = xb;                      // x_bf16 dead after GEMM1

  cvt_kernel<<<12288, 256, 0, stream>>>(x, xb, 3145728);
  transpose_cvt<<<dim3(72, 24), dim3(32, 8), 0, stream>>>(Wqkv, wqt, 768, 2304);
  transpose_cvt<<<dim3(24, 24), dim3(32, 8), 0, stream>>>(Wproj, wpt, 768, 768);
  gemm8p_kernel<12, 8, 1><<<1152, 512, 0, stream>>>(xb, wqt, bqkv, qkv, 32768, 2304);
  attn_kernel<<<256, 256, 0, stream>>>(qkv, temp, y);
  gemm8p_kernel<12, 4, 0><<<768, 512, 0, stream>>>(y, wpt, bproj, out, 32768, 768);
}

// Round 4
// 316.064 us; speedup vs baseline: 1.1964x; 1.0016x over previous
//
#include <hip/hip_runtime.h>
#include <hip/hip_bf16.h>

// XCAttention: B=8, N=4096, C=768, H=32, D=24
// K0a: x fp32->bf16; K0b: W transposed->bf16; K1: qkv GEMM (8-phase 256x256);
// K2: per-(b,h) XCA core; K3: proj GEMM (8-phase 128x256), fp32 out.

#define DEVI __device__ __forceinline__

typedef __attribute__((ext_vector_type(8))) short bf16x8;
typedef __attribute__((ext_vector_type(4))) float f32x4;
typedef unsigned int u32;
typedef unsigned short u16;

DEVI u16 f2bf(float f) {  // RNE float->bf16
  union { float f; u32 u; } x; x.f = f;
  u32 r = x.u + 0x7FFFu + ((x.u >> 16) & 1u);
  return (u16)(r >> 16);
}

DEVI void gload_lds16(const void* g, void* l) {
  __builtin_amdgcn_global_load_lds((__attribute__((address_space(1))) void*)g,
                                   (__attribute__((address_space(3))) void*)l, 16, 0, 0);
}

// ---------------- K0a: fp32 -> bf16 convert ----------------
__global__ __launch_bounds__(256) void cvt_kernel(const float* __restrict__ in,
                                                  u16* __restrict__ out, int n8) {
  int i = blockIdx.x * 256 + threadIdx.x;
  if (i >= n8) return;
  long o = (long)i * 8;
  float4 a = *(const float4*)(in + o);
  float4 b = *(const float4*)(in + o + 4);
  uint4 v;
  v.x = f2bf(a.x) | ((u32)f2bf(a.y) << 16);
  v.y = f2bf(a.z) | ((u32)f2bf(a.w) << 16);
  v.z = f2bf(b.x) | ((u32)f2bf(b.y) << 16);
  v.w = f2bf(b.z) | ((u32)f2bf(b.w) << 16);
  *(uint4*)(out + o) = v;
}

// ---------------- K0b: W (K x N fp32) -> Wt (N x K bf16) ----------------
__global__ __launch_bounds__(256) void transpose_cvt(const float* __restrict__ W,
                                                     u16* __restrict__ Wt, int K, int N) {
  __shared__ float tile[32][33];
  int n0 = blockIdx.x * 32, k0 = blockIdx.y * 32;
  int tx = threadIdx.x, ty = threadIdx.y;  // (32,8)
  #pragma unroll
  for (int i = 0; i < 4; ++i)
    tile[ty + 8 * i][tx] = W[(long)(k0 + ty + 8 * i) * N + n0 + tx];
  __syncthreads();
  #pragma unroll
  for (int i = 0; i < 4; ++i)
    Wt[(long)(n0 + ty + 8 * i) * K + k0 + tx] = f2bf(tile[tx][ty + 8 * i]);
}

// ---------------- 8-phase BMx256 bf16 MFMA GEMM ----------------
// A: M x K row-major bf16. Bt: N x K row-major bf16. C = A@Bt^T + bias.
// 512 thr = 8 waves (2Mx4N), per-wave (BM/2)x64, BK=64, 2 K-tile dbuf slots.
// LDS per A slot: [ks(2)][row(BM)][32 bf16] (64B rows); B slot 256 rows.
// st_16x32 swizzle byte ^= ((byte>>9)&1)<<5 (pre-swizzled gload source + ds_read addr).
// Counted waits only: no lgkmcnt(0) in loop (compiler emits counted waits from
// data deps; reads are consumed one phase after issue), vmcnt(4) twice per 2 tiles.

#define MFMAQ(s, bs, q)                                                        \
  { _Pragma("unroll") for (int mi = 0; mi < MI; ++mi)                          \
    _Pragma("unroll") for (int n = 0; n < 4; ++n) {                            \
      acc[MI*(q)+mi][n] = __builtin_amdgcn_mfma_f32_16x16x32_bf16(             \
          aR[s][mi*2+0], bR[bs][n*2+0], acc[MI*(q)+mi][n], 0, 0, 0);           \
      acc[MI*(q)+mi][n] = __builtin_amdgcn_mfma_f32_16x16x32_bf16(             \
          aR[s][mi*2+1], bR[bs][n*2+1], acc[MI*(q)+mi][n], 0, 0, 0); } }

#define RDA(s, slot, q)                                                        \
  { _Pragma("unroll") for (int mi = 0; mi < MI; ++mi)                          \
    _Pragma("unroll") for (int ks = 0; ks < 2; ++ks)                           \
      aR[s][mi*2+ks] = *(const bf16x8*)(lds + (slot)*SLOT_A + ks*KS_A +        \
                                        (MI*(q)+mi)*1024 + pA0); }

#define RDB(bs, slot)                                                          \
  { _Pragma("unroll") for (int n = 0; n < 4; ++n)                              \
    _Pragma("unroll") for (int ks = 0; ks < 2; ++ks)                           \
      bR[bs][n*2+ks] = *(const bf16x8*)(lds + BOFF + (slot)*32768 + ks*16384 + \
                                        n*1024 + pB0); }

#define STAGE_A(slot, ktile)                                                   \
  { _Pragma("unroll") for (int j_ = 0; j_ < JA; ++j_)                          \
    _Pragma("unroll") for (int h_ = 0; h_ < 2; ++h_)                           \
      gload_lds16(Ag + soff[j_] + (ktile) * 64 + h_ * 32,                      \
                  lds + (slot)*SLOT_A + h_*KS_A + sdst + j_*8192); }

#define STAGE_B(slot, ktile)                                                   \
  { _Pragma("unroll") for (int j_ = 0; j_ < 2; ++j_)                           \
    _Pragma("unroll") for (int h_ = 0; h_ < 2; ++h_)                           \
      gload_lds16(Bg + soff[j_] + (ktile) * 64 + h_ * 32,                      \
                  lds + BOFF + (slot)*32768 + h_*16384 + sdst + j_*8192); }

#define PHASE_TAIL(SET, BS, Q)                                                 \
  __builtin_amdgcn_sched_barrier(0);                                           \
  __builtin_amdgcn_s_barrier();                                                \
  __builtin_amdgcn_sched_barrier(0);                                           \
  __builtin_amdgcn_s_setprio(1);                                               \
  MFMAQ(SET, BS, Q);                                                           \
  __builtin_amdgcn_s_setprio(0);                                               \
  __builtin_amdgcn_s_barrier();                                                \
  __builtin_amdgcn_sched_barrier(0);

template<int NT, int MFRAG, int BF16_OUT>
__global__ __launch_bounds__(512, 2) void gemm8p_kernel(
    const u16* __restrict__ A, const u16* __restrict__ Bt,
    const float* __restrict__ bias, void* __restrict__ Cout,
    int M, int N) {
  constexpr int K = NT * 64;
  constexpr int MI = MFRAG / 4;        // m-frags per quadrant
  constexpr int BM = MFRAG * 32;       // 256 or 128
  constexpr int SLOT_A = BM * 128;     // bytes per A slot
  constexpr int KS_A = BM * 64;
  constexpr int BOFF = 2 * SLOT_A;     // B region base
  constexpr int JA = BM / 128;         // per-thread A stage chunks
  __shared__ __attribute__((aligned(128))) char lds[BOFF + 65536];

  int nbx = N >> 8;
  int nwg = gridDim.x;
  int bid = blockIdx.x;
  bid = (bid & 7) * (nwg >> 3) + (bid >> 3);  // bijective XCD swizzle (nwg%8==0)
  int bx = bid % nbx, by = bid / nbx;

  int t = threadIdx.x;
  int w = t >> 6, l = t & 63;
  int wr = w >> 2, wc = w & 3;
  int l16 = l & 15, l4 = l >> 4;

  // frag-read byte bases (swizzled)
  int rA = wr * (MFRAG * 16) + l16, rB = wc * 64 + l16;
  int cbb = l4 * 16;
  int pA0 = rA * 64 + (cbb ^ (((rA >> 3) & 1) << 5));
  int pB0 = rB * 64 + (cbb ^ (((rB >> 3) & 1) << 5));

  // stage source offsets (inverse-swizzled) for chunks t, t+512
  int soff[2];
  #pragma unroll
  for (int j = 0; j < 2; ++j) {
    int pin = (j * 512 + t) * 16;
    int inb = pin ^ (((pin >> 9) & 1) << 5);
    soff[j] = (inb >> 6) * K + ((inb & 63) >> 1);
  }
  const u16* Ag = A + (long)by * BM * K;
  const u16* Bg = Bt + (long)bx * 256 * K;
  int sdst = w * 1024;  // wave-uniform LDS stage dest base (bytes)

  f32x4 acc[MFRAG][4] = {};
  bf16x8 aR[2][2 * MI], bR[2][8];

  // ---- prologue: A(0),B(0)->slot0, B(1)->slot1 ----
  STAGE_A(0, 0);
  STAGE_B(0, 0);
  STAGE_B(1, 1);
  asm volatile("s_waitcnt vmcnt(4)" ::: "memory");
  __builtin_amdgcn_s_barrier();
  RDA(0, 0, 0);
  RDB(0, 0);

  const int niter = NT / 2;
  for (int it = 0; it < niter; ++it) {
    int kt = it * 2;
    bool nl = (it < niter - 1);
    // pi0: MFMA q0 tile kt (slot0,set0,bR0); rd mq1->set1; stage A(kt+1)->slot1
    RDA(1, 0, 1);
    STAGE_A(1, kt + 1);
    PHASE_TAIL(0, 0, 0)
    // pi1: MFMA q1; rd mq2->set0; stage B(kt+2)->slot0
    RDA(0, 0, 2);
    if (nl) STAGE_B(0, kt + 2);
    PHASE_TAIL(1, 0, 1)
    // pi2: MFMA q2; rd mq3->set1; vmcnt
    RDA(1, 0, 3);
    if (nl) asm volatile("s_waitcnt vmcnt(4)" ::: "memory");
    else    asm volatile("s_waitcnt vmcnt(0)" ::: "memory");
    PHASE_TAIL(0, 0, 2)
    // pi3: MFMA q3; rd mq0(kt+1,slot1)->set0 + B(kt+1)->bR1
    RDA(0, 1, 0);
    RDB(1, 1);
    PHASE_TAIL(1, 0, 3)
    // pi4: tile kt+1: MFMA q0 (set0,bR1); rd mq1->set1; stage A(kt+2)->slot0
    RDA(1, 1, 1);
    if (nl) STAGE_A(0, kt + 2);
    PHASE_TAIL(0, 1, 0)
    // pi5: MFMA q1; rd mq2->set0; stage B(kt+3)->slot1
    RDA(0, 1, 2);
    if (nl) STAGE_B(1, kt + 3);
    PHASE_TAIL(1, 1, 1)
    // pi6: MFMA q2; rd mq3->set1; vmcnt
    RDA(1, 1, 3);
    if (nl) asm volatile("s_waitcnt vmcnt(4)" ::: "memory");
    PHASE_TAIL(0, 1, 2)
    // pi7: MFMA q3; rd mq0(kt+2,slot0)->set0 + B(kt+2)->bR0
    if (nl) { RDA(0, 0, 0); RDB(0, 0); }
    PHASE_TAIL(1, 1, 3)
  }

  // ---- epilogue ----
  #pragma unroll
  for (int m = 0; m < MFRAG; ++m) {
    int row0 = by * BM + wr * (MFRAG * 16) + m * 16 + l4 * 4;
    #pragma unroll
    for (int n = 0; n < 4; ++n) {
      int col = bx * 256 + wc * 64 + n * 16 + l16;
      float bv = bias[col];
      #pragma unroll
      for (int j = 0; j < 4; ++j) {
        long idx = (long)(row0 + j) * N + col;
        float v = acc[m][n][j] + bv;
        if (BF16_OUT) ((u16*)Cout)[idx] = f2bf(v);
        else          ((float*)Cout)[idx] = v;
      }
    }
  }
}

// ---------------- K2: per-(b,h) XCA core ----------------
__global__ __launch_bounds__(256) void attn_kernel(const u16* __restrict__ qkv,
                                                   const float* __restrict__ temperature,
                                                   u16* __restrict__ yout) {
  __shared__ u16 qt[32][136];
  __shared__ u16 kt[32][136];
  __shared__ u16 vl[128][40];
  __shared__ u16 attnb[32][40];
  __shared__ float Gs[32][33];
  __shared__ float sq[32];
  __shared__ float sk[32];

  int bid = blockIdx.x;
  int b = bid >> 5, h = bid & 31;
  int t = threadIdx.x;
  int w = t >> 6, l = t & 63;
  int l16 = l & 15, l4 = l >> 4;
  int fm = w >> 1, fn = w & 1;

  for (int i = t; i < 32 * 136; i += 256) { qt[0][i] = 0; kt[0][i] = 0; }
  for (int i = t; i < 128 * 40; i += 256) vl[0][i] = 0;
  for (int i = t; i < 32 * 40; i += 256) attnb[0][i] = 0;
  __syncthreads();

  f32x4 accG = {}, accQ = {}, accK = {};
  const u16* qbase = qkv + (long)b * 4096 * 2304 + h * 24;

  for (int nc = 0; nc < 32; ++nc) {
    int n0 = nc * 128;
    #pragma unroll
    for (int i = 0; i < 6; ++i) {
      int idx = t + 256 * i;
      int n = idx / 12, dw = idx % 12;
      const u16* p = qbase + (long)(n0 + n) * 2304 + dw * 2;
      u32 uq = *(const u32*)p;
      u32 uk = *(const u32*)(p + 768);
      qt[dw * 2][n] = (u16)uq; qt[dw * 2 + 1][n] = (u16)(uq >> 16);
      kt[dw * 2][n] = (u16)uk; kt[dw * 2 + 1][n] = (u16)(uk >> 16);
    }
    __syncthreads();
    #pragma unroll
    for (int ks = 0; ks < 4; ++ks) {
      int koff = ks * 32 + l4 * 8;
      bf16x8 qa = *(const bf16x8*)&qt[fm * 16 + l16][koff];
      bf16x8 qb = *(const bf16x8*)&qt[fn * 16 + l16][koff];
      bf16x8 ka = *(const bf16x8*)&kt[fm * 16 + l16][koff];
      bf16x8 kb = *(const bf16x8*)&kt[fn * 16 + l16][koff];
      accG = __builtin_amdgcn_mfma_f32_16x16x32_bf16(qa, kb, accG, 0, 0, 0);
      accQ = __builtin_amdgcn_mfma_f32_16x16x32_bf16(qa, qb, accQ, 0, 0, 0);
      accK = __builtin_amdgcn_mfma_f32_16x16x32_bf16(ka, kb, accK, 0, 0, 0);
    }
    __syncthreads();
  }

  #pragma unroll
  for (int j = 0; j < 4; ++j) Gs[fm * 16 + l4 * 4 + j][fn * 16 + l16] = accG[j];
  if (fm == fn) {
    #pragma unroll
    for (int j = 0; j < 4; ++j)
      if (l4 * 4 + j == l16) { sq[fm * 16 + l16] = accQ[j]; sk[fm * 16 + l16] = accK[j]; }
  }
  __syncthreads();

  if (t < 24) {
    float nq = fmaxf(sqrtf(fmaxf(sq[t], 0.f)), 1e-12f);
    float tmp = temperature[h];
    float p[24]; float mx = -1e30f;
    #pragma unroll
    for (int e = 0; e < 24; ++e) {
      float nk = fmaxf(sqrtf(fmaxf(sk[e], 0.f)), 1e-12f);
      float a = Gs[t][e] / (nq * nk) * tmp;
      p[e] = a; mx = fmaxf(mx, a);
    }
    float s = 0.f;
    #pragma unroll
    for (int e = 0; e < 24; ++e) { p[e] = __expf(p[e] - mx); s += p[e]; }
    float inv = 1.f / s;
    #pragma unroll
    for (int e = 0; e < 24; ++e) attnb[t][e] = f2bf(p[e] * inv);
  }
  __syncthreads();

  bf16x8 af0 = *(const bf16x8*)&attnb[l16][l4 * 8];
  bf16x8 af1 = *(const bf16x8*)&attnb[16 + l16][l4 * 8];
  const u16* vbase = qbase + 1536;
  u16* ybase = yout + (long)(h * 8 + b) * 24 * 4096;

  for (int nc = 0; nc < 32; ++nc) {
    int n0 = nc * 128;
    #pragma unroll
    for (int i = 0; i < 6; ++i) {
      int idx = t + 256 * i;
      int n = idx / 12, dw = idx % 12;
      u32 uv = *(const u32*)(vbase + (long)(n0 + n) * 2304 + dw * 2);
      *(u32*)&vl[n][dw * 2] = uv;
    }
    __syncthreads();
    f32x4 z = {};
    #pragma unroll
    for (int fnn = 0; fnn < 2; ++fnn) {
      int ncol = w * 32 + fnn * 16 + l16;
      bf16x8 bv = *(const bf16x8*)&vl[ncol][l4 * 8];
      f32x4 y0 = __builtin_amdgcn_mfma_f32_16x16x32_bf16(af0, bv, z, 0, 0, 0);
      f32x4 y1 = __builtin_amdgcn_mfma_f32_16x16x32_bf16(af1, bv, z, 0, 0, 0);
      int gn = n0 + ncol;
      #pragma unroll
      for (int j = 0; j < 4; ++j) {
        int d0 = l4 * 4 + j;
        ybase[(long)d0 * 4096 + gn] = f2bf(y0[j]);
        int d1 = 16 + d0;
        if (d1 < 24) ybase[(long)d1 * 4096 + gn] = f2bf(y1[j]);
      }
    }
    __syncthreads();
  }
}

extern "C" void kernel_launch(void* const* d_in, const int* in_sizes, int n_in,
                              void* d_out, int out_size, void* d_ws, size_t ws_size,
                              hipStream_t stream) {
  const float* x     = (const float*)d_in[0];
  const float* Wqkv  = (const float*)d_in[1];
  const float* bqkv  = (const float*)d_in[2];
  const float* temp  = (const float*)d_in[3];
  const float* Wproj = (const float*)d_in[4];
  const float* bproj = (const float*)d_in[5];
  float* out = (float*)d_out;

  char* ws = (char*)d_ws;
  u16* xb  = (u16*)(ws);              // 32768x768 bf16
  u16* wqt = (u16*)(ws + 50331648);   // 2304x768  bf16
  u16* wpt = (u16*)(ws + 53870592);   // 768x768   bf16
  u16* qkv = (u16*)(ws + 55050240);   // 32768x2304 bf16
  u16* y   = xb;                      // x_bf16 dead after GEMM1

  cvt_kernel<<<12288, 256, 0, stream>>>(x, xb, 3145728);
  transpose_cvt<<<dim3(72, 24), dim3(32, 8), 0, stream>>>(Wqkv, wqt, 768, 2304);
  transpose_cvt<<<dim3(24, 24), dim3(32, 8), 0, stream>>>(Wproj, wpt, 768, 768);
  gemm8p_kernel<12, 8, 1><<<1152, 512, 0, stream>>>(xb, wqt, bqkv, qkv, 32768, 2304);
  attn_kernel<<<256, 256, 0, stream>>>(qkv, temp, y);
  gemm8p_kernel<12, 4, 0><<<768, 512, 0, stream>>>(y, wpt, bproj, out, 32768, 768);
}

// Round 5
// 314.097 us; speedup vs baseline: 1.2039x; 1.0063x over previous
//
#include <hip/hip_runtime.h>
#include <hip/hip_bf16.h>

// XCAttention: B=8, N=4096, C=768, H=32, D=24
// K0a: x fp32->bf16; K0b: W transposed->bf16; K1: qkv GEMM (128x128, 2 blocks/CU);
// K2: per-(b,h) XCA core; K3: proj GEMM (same structure), fp32 out.

#define DEVI __device__ __forceinline__

typedef __attribute__((ext_vector_type(8))) short bf16x8;
typedef __attribute__((ext_vector_type(4))) float f32x4;
typedef unsigned int u32;
typedef unsigned short u16;

DEVI u16 f2bf(float f) {  // RNE float->bf16
  union { float f; u32 u; } x; x.f = f;
  u32 r = x.u + 0x7FFFu + ((x.u >> 16) & 1u);
  return (u16)(r >> 16);
}

DEVI void gload_lds16(const void* g, void* l) {
  __builtin_amdgcn_global_load_lds((__attribute__((address_space(1))) void*)g,
                                   (__attribute__((address_space(3))) void*)l, 16, 0, 0);
}

// ---------------- K0a: fp32 -> bf16 convert ----------------
__global__ __launch_bounds__(256) void cvt_kernel(const float* __restrict__ in,
                                                  u16* __restrict__ out, int n8) {
  int i = blockIdx.x * 256 + threadIdx.x;
  if (i >= n8) return;
  long o = (long)i * 8;
  float4 a = *(const float4*)(in + o);
  float4 b = *(const float4*)(in + o + 4);
  uint4 v;
  v.x = f2bf(a.x) | ((u32)f2bf(a.y) << 16);
  v.y = f2bf(a.z) | ((u32)f2bf(a.w) << 16);
  v.z = f2bf(b.x) | ((u32)f2bf(b.y) << 16);
  v.w = f2bf(b.z) | ((u32)f2bf(b.w) << 16);
  *(uint4*)(out + o) = v;
}

// ---------------- K0b: W (K x N fp32) -> Wt (N x K bf16) ----------------
__global__ __launch_bounds__(256) void transpose_cvt(const float* __restrict__ W,
                                                     u16* __restrict__ Wt, int K, int N) {
  __shared__ float tile[32][33];
  int n0 = blockIdx.x * 32, k0 = blockIdx.y * 32;
  int tx = threadIdx.x, ty = threadIdx.y;  // (32,8)
  #pragma unroll
  for (int i = 0; i < 4; ++i)
    tile[ty + 8 * i][tx] = W[(long)(k0 + ty + 8 * i) * N + n0 + tx];
  __syncthreads();
  #pragma unroll
  for (int i = 0; i < 4; ++i)
    Wt[(long)(n0 + ty + 8 * i) * K + k0 + tx] = f2bf(tile[tx][ty + 8 * i]);
}

// ---------------- 128x128 bf16 MFMA GEMM, 2 blocks/CU ----------------
// A: M x K row-major bf16. Bt: N x K row-major bf16. C = A@Bt^T + bias.
// 512 thr = 8 waves (2M x 4N), per-wave 64x32, BK=64, 2 K-tile dbuf slots.
// LDS 64KB total (A 2x16KB, B 2x16KB) -> 2 blocks/CU = 4 waves/SIMD; cross-block
// overlap fills barrier/drain windows (m114 mechanism).
// Slot layout: [ks(2)][row(128)][32 bf16] (64B rows), st_16x32 swizzle
// byte^=((byte>>9)&1)<<5 (inverse-swizzled gload source, swizzled ds_read addr).
// Per K-tile phase: STAGE(kt+1)->other slot; counted vmcnt(4); barrier;
// 12 ds_read_b128 + 16 MFMA (compiler-counted lgkm, setprio(1)); barrier.
template<int NT, int BF16_OUT>
__global__ __launch_bounds__(512, 4) void gemm2b_kernel(
    const u16* __restrict__ A, const u16* __restrict__ Bt,
    const float* __restrict__ bias, void* __restrict__ Cout,
    int M, int N) {
  constexpr int K = NT * 64;
  __shared__ __attribute__((aligned(128))) char lds[65536];

  int nbx = N >> 7;
  int nwg = gridDim.x;
  int bid = blockIdx.x;
  bid = (bid & 7) * (nwg >> 3) + (bid >> 3);  // bijective XCD swizzle (nwg%8==0)
  int bx = bid % nbx, by = bid / nbx;

  int t = threadIdx.x;
  int w = t >> 6, l = t & 63;
  int wr = w >> 2, wc = w & 3;
  int l16 = l & 15, l4 = l >> 4;

  // swizzled frag-read byte bases (within-slot); row-bit3 = l16 bit3 only
  int cbb = (l4 * 16) ^ ((l16 & 8) << 2);
  int pA0 = (wr * 64 + l16) * 64 + cbb;            // + s*16384 + ks*8192 + mi*1024
  int pB0 = 32768 + (wc * 32 + l16) * 64 + cbb;    // + s*16384 + ks*8192 + n*1024

  // inverse-swizzled stage source offset (per-thread), round j adds j*32 elems
  int pin = t * 16;
  int lam = pin ^ (((pin >> 9) & 1) << 5);
  int soff = (lam >> 6) * K + ((lam & 63) >> 1);

  const u16* Ag = A + (long)by * 128 * K;
  const u16* Bg = Bt + (long)bx * 128 * K;
  int sdA = w * 1024;  // wave-uniform LDS stage dest base (within 8KB round)

  f32x4 acc[4][2] = {};

  // prologue: stage tile 0 -> slot 0
  #pragma unroll
  for (int j = 0; j < 2; ++j) {
    gload_lds16(Ag + soff + j * 32, lds + j * 8192 + sdA);
    gload_lds16(Bg + soff + j * 32, lds + 32768 + j * 8192 + sdA);
  }

  for (int kt = 0; kt < NT; ++kt) {
    int s = kt & 1;
    if (kt + 1 < NT) {
      #pragma unroll
      for (int j = 0; j < 2; ++j) {
        gload_lds16(Ag + soff + (kt + 1) * 64 + j * 32,
                    lds + (s ^ 1) * 16384 + j * 8192 + sdA);
        gload_lds16(Bg + soff + (kt + 1) * 64 + j * 32,
                    lds + 32768 + (s ^ 1) * 16384 + j * 8192 + sdA);
      }
      asm volatile("s_waitcnt vmcnt(4)" ::: "memory");  // waits tile kt's 4, kt+1 in flight
    } else {
      asm volatile("s_waitcnt vmcnt(0)" ::: "memory");
    }
    __builtin_amdgcn_sched_barrier(0);
    __builtin_amdgcn_s_barrier();
    __builtin_amdgcn_sched_barrier(0);

    bf16x8 aF[4][2], bF[2][2];
    #pragma unroll
    for (int mi = 0; mi < 4; ++mi)
      #pragma unroll
      for (int ks = 0; ks < 2; ++ks)
        aF[mi][ks] = *(const bf16x8*)(lds + s * 16384 + ks * 8192 + mi * 1024 + pA0);
    #pragma unroll
    for (int n = 0; n < 2; ++n)
      #pragma unroll
      for (int ks = 0; ks < 2; ++ks)
        bF[n][ks] = *(const bf16x8*)(lds + s * 16384 + ks * 8192 + n * 1024 + pB0);

    __builtin_amdgcn_s_setprio(1);
    #pragma unroll
    for (int mi = 0; mi < 4; ++mi)
      #pragma unroll
      for (int n = 0; n < 2; ++n) {
        acc[mi][n] = __builtin_amdgcn_mfma_f32_16x16x32_bf16(aF[mi][0], bF[n][0], acc[mi][n], 0, 0, 0);
        acc[mi][n] = __builtin_amdgcn_mfma_f32_16x16x32_bf16(aF[mi][1], bF[n][1], acc[mi][n], 0, 0, 0);
      }
    __builtin_amdgcn_s_setprio(0);
    __builtin_amdgcn_s_barrier();
    __builtin_amdgcn_sched_barrier(0);
  }

  // epilogue
  #pragma unroll
  for (int mi = 0; mi < 4; ++mi) {
    int row0 = by * 128 + wr * 64 + mi * 16 + l4 * 4;
    #pragma unroll
    for (int n = 0; n < 2; ++n) {
      int col = bx * 128 + wc * 32 + n * 16 + l16;
      float bv = bias[col];
      #pragma unroll
      for (int j = 0; j < 4; ++j) {
        long idx = (long)(row0 + j) * N + col;
        float v = acc[mi][n][j] + bv;
        if (BF16_OUT) ((u16*)Cout)[idx] = f2bf(v);
        else          ((float*)Cout)[idx] = v;
      }
    }
  }
}

// ---------------- K2: per-(b,h) XCA core ----------------
__global__ __launch_bounds__(256) void attn_kernel(const u16* __restrict__ qkv,
                                                   const float* __restrict__ temperature,
                                                   u16* __restrict__ yout) {
  __shared__ u16 qt[32][136];
  __shared__ u16 kt[32][136];
  __shared__ u16 vl[128][40];
  __shared__ u16 attnb[32][40];
  __shared__ float Gs[32][33];
  __shared__ float sq[32];
  __shared__ float sk[32];

  int bid = blockIdx.x;
  int b = bid >> 5, h = bid & 31;
  int t = threadIdx.x;
  int w = t >> 6, l = t & 63;
  int l16 = l & 15, l4 = l >> 4;
  int fm = w >> 1, fn = w & 1;

  for (int i = t; i < 32 * 136; i += 256) { qt[0][i] = 0; kt[0][i] = 0; }
  for (int i = t; i < 128 * 40; i += 256) vl[0][i] = 0;
  for (int i = t; i < 32 * 40; i += 256) attnb[0][i] = 0;
  __syncthreads();

  f32x4 accG = {}, accQ = {}, accK = {};
  const u16* qbase = qkv + (long)b * 4096 * 2304 + h * 24;

  for (int nc = 0; nc < 32; ++nc) {
    int n0 = nc * 128;
    #pragma unroll
    for (int i = 0; i < 6; ++i) {
      int idx = t + 256 * i;
      int n = idx / 12, dw = idx % 12;
      const u16* p = qbase + (long)(n0 + n) * 2304 + dw * 2;
      u32 uq = *(const u32*)p;
      u32 uk = *(const u32*)(p + 768);
      qt[dw * 2][n] = (u16)uq; qt[dw * 2 + 1][n] = (u16)(uq >> 16);
      kt[dw * 2][n] = (u16)uk; kt[dw * 2 + 1][n] = (u16)(uk >> 16);
    }
    __syncthreads();
    #pragma unroll
    for (int ks = 0; ks < 4; ++ks) {
      int koff = ks * 32 + l4 * 8;
      bf16x8 qa = *(const bf16x8*)&qt[fm * 16 + l16][koff];
      bf16x8 qb = *(const bf16x8*)&qt[fn * 16 + l16][koff];
      bf16x8 ka = *(const bf16x8*)&kt[fm * 16 + l16][koff];
      bf16x8 kb = *(const bf16x8*)&kt[fn * 16 + l16][koff];
      accG = __builtin_amdgcn_mfma_f32_16x16x32_bf16(qa, kb, accG, 0, 0, 0);
      accQ = __builtin_amdgcn_mfma_f32_16x16x32_bf16(qa, qb, accQ, 0, 0, 0);
      accK = __builtin_amdgcn_mfma_f32_16x16x32_bf16(ka, kb, accK, 0, 0, 0);
    }
    __syncthreads();
  }

  #pragma unroll
  for (int j = 0; j < 4; ++j) Gs[fm * 16 + l4 * 4 + j][fn * 16 + l16] = accG[j];
  if (fm == fn) {
    #pragma unroll
    for (int j = 0; j < 4; ++j)
      if (l4 * 4 + j == l16) { sq[fm * 16 + l16] = accQ[j]; sk[fm * 16 + l16] = accK[j]; }
  }
  __syncthreads();

  if (t < 24) {
    float nq = fmaxf(sqrtf(fmaxf(sq[t], 0.f)), 1e-12f);
    float tmp = temperature[h];
    float p[24]; float mx = -1e30f;
    #pragma unroll
    for (int e = 0; e < 24; ++e) {
      float nk = fmaxf(sqrtf(fmaxf(sk[e], 0.f)), 1e-12f);
      float a = Gs[t][e] / (nq * nk) * tmp;
      p[e] = a; mx = fmaxf(mx, a);
    }
    float s = 0.f;
    #pragma unroll
    for (int e = 0; e < 24; ++e) { p[e] = __expf(p[e] - mx); s += p[e]; }
    float inv = 1.f / s;
    #pragma unroll
    for (int e = 0; e < 24; ++e) attnb[t][e] = f2bf(p[e] * inv);
  }
  __syncthreads();

  bf16x8 af0 = *(const bf16x8*)&attnb[l16][l4 * 8];
  bf16x8 af1 = *(const bf16x8*)&attnb[16 + l16][l4 * 8];
  const u16* vbase = qbase + 1536;
  u16* ybase = yout + (long)(h * 8 + b) * 24 * 4096;

  for (int nc = 0; nc < 32; ++nc) {
    int n0 = nc * 128;
    #pragma unroll
    for (int i = 0; i < 6; ++i) {
      int idx = t + 256 * i;
      int n = idx / 12, dw = idx % 12;
      u32 uv = *(const u32*)(vbase + (long)(n0 + n) * 2304 + dw * 2);
      *(u32*)&vl[n][dw * 2] = uv;
    }
    __syncthreads();
    f32x4 z = {};
    #pragma unroll
    for (int fnn = 0; fnn < 2; ++fnn) {
      int ncol = w * 32 + fnn * 16 + l16;
      bf16x8 bv = *(const bf16x8*)&vl[ncol][l4 * 8];
      f32x4 y0 = __builtin_amdgcn_mfma_f32_16x16x32_bf16(af0, bv, z, 0, 0, 0);
      f32x4 y1 = __builtin_amdgcn_mfma_f32_16x16x32_bf16(af1, bv, z, 0, 0, 0);
      int gn = n0 + ncol;
      #pragma unroll
      for (int j = 0; j < 4; ++j) {
        int d0 = l4 * 4 + j;
        ybase[(long)d0 * 4096 + gn] = f2bf(y0[j]);
        int d1 = 16 + d0;
        if (d1 < 24) ybase[(long)d1 * 4096 + gn] = f2bf(y1[j]);
      }
    }
    __syncthreads();
  }
}

extern "C" void kernel_launch(void* const* d_in, const int* in_sizes, int n_in,
                              void* d_out, int out_size, void* d_ws, size_t ws_size,
                              hipStream_t stream) {
  const float* x     = (const float*)d_in[0];
  const float* Wqkv  = (const float*)d_in[1];
  const float* bqkv  = (const float*)d_in[2];
  const float* temp  = (const float*)d_in[3];
  const float* Wproj = (const float*)d_in[4];
  const float* bproj = (const float*)d_in[5];
  float* out = (float*)d_out;

  char* ws = (char*)d_ws;
  u16* xb  = (u16*)(ws);              // 32768x768 bf16
  u16* wqt = (u16*)(ws + 50331648);   // 2304x768  bf16
  u16* wpt = (u16*)(ws + 53870592);   // 768x768   bf16
  u16* qkv = (u16*)(ws + 55050240);   // 32768x2304 bf16
  u16* y   = xb;                      // x_bf16 dead after GEMM1

  cvt_kernel<<<12288, 256, 0, stream>>>(x, xb, 3145728);
  transpose_cvt<<<dim3(72, 24), dim3(32, 8), 0, stream>>>(Wqkv, wqt, 768, 2304);
  transpose_cvt<<<dim3(24, 24), dim3(32, 8), 0, stream>>>(Wproj, wpt, 768, 768);
  gemm2b_kernel<12, 1><<<4608, 512, 0, stream>>>(xb, wqt, bqkv, qkv, 32768, 2304);
  attn_kernel<<<256, 256, 0, stream>>>(qkv, temp, y);
  gemm2b_kernel<12, 0><<<1536, 512, 0, stream>>>(y, wpt, bproj, out, 32768, 768);
}